// Round 1
// baseline (148.311 us; speedup 1.0000x reference)
//
#include <hip/hip_runtime.h>
#include <math.h>

// RRoIAlign: features (8,32,160,160) f32, rois (1024,6) f32
// out (1024,32,8,64) f32.
// POOLED_H=8, POOLED_W=64, SPATIAL_SCALE=0.25
//
// Kernel 1: per-roi affine transform precompute (hoists trig; 1024 threads).
// Kernel 2: one thread per output element; coalesced stores on pw.
// fp contract OFF in geometry path: round(floor(x+0.5)) pixel selection is
// ulp-sensitive vs the numpy reference; fma fusion would guarantee drift.

#define C_ 32
#define H_ 160
#define W_ 160
#define PH_ 8
#define PW_ 64

__global__ __launch_bounds__(256) void roi_prep(const float* __restrict__ rois,
                                                float* __restrict__ g, int N) {
#pragma clang fp contract(off)
    int n = blockIdx.x * 256 + threadIdx.x;
    if (n >= N) return;
    const float* r = rois + n * 6;
    float bidx = r[0];
    float cx = r[1], cy = r[2], hh = r[3], ww = r[4], ang = r[5];
    // theta = ang * float32(pi/180); trig in double -> correctly-rounded f32
    float theta = ang * 0.017453292519943295f;
    double td = (double)theta;
    float a = (float)cos(td);
    float s = (float)sin(td);
    // Sx = ww*0.25/64, Sy = hh*0.25/8 : power-of-2 scales, exact
    float Sx = (ww * 0.25f) / 64.0f;
    float Sy = (hh * 0.25f) / 8.0f;
    float Dx = cx * 0.25f;
    float Dy = cy * 0.25f;
    float M00 = a * Sx;
    float M01 = s * Sy;
    // M02 = (a*Sx)*dx + (b*Sy)*dy + Dx, dx=-32, dy=-4 (exact pow2 muls)
    float M02 = ((M00 * -32.0f) + (M01 * -4.0f)) + Dx;
    float M10 = (-s) * Sx;
    float M11 = a * Sy;
    float M12 = ((M10 * -32.0f) + (M11 * -4.0f)) + Dy;
    float* o = g + n * 8;
    o[0] = bidx;
    o[1] = M00; o[2] = M01; o[3] = M02;
    o[4] = M10; o[5] = M11; o[6] = M12;
    o[7] = 0.0f;
}

__global__ __launch_bounds__(256) void rroi_main(const float* __restrict__ feat,
                                                 const float* __restrict__ g,
                                                 float* __restrict__ out,
                                                 int total) {
#pragma clang fp contract(off)
    int idx = blockIdx.x * 256 + threadIdx.x;
    if (idx >= total) return;
    int pw = idx & 63;
    int ph = (idx >> 6) & 7;
    int c  = (idx >> 9) & 31;
    int n  = idx >> 14;

    const float* gg = g + n * 8;
    int   b   = (int)gg[0];
    float M00 = gg[1], M01 = gg[2], M02 = gg[3];
    float M10 = gg[4], M11 = gg[5], M12 = gg[6];

    float pwf  = (float)pw, phf = (float)ph;
    float pwf1 = pwf + 1.0f, phf1 = phf + 1.0f;

    // corners, reference op order: (M00*px + M01*py) + M02
    float X0 = (M00 * pwf  + M01 * phf ) + M02;
    float X1 = (M00 * pwf  + M01 * phf1) + M02;
    float X2 = (M00 * pwf1 + M01 * phf ) + M02;
    float X3 = (M00 * pwf1 + M01 * phf1) + M02;
    float Y0 = (M10 * pwf  + M11 * phf ) + M12;
    float Y1 = (M10 * pwf  + M11 * phf1) + M12;
    float Y2 = (M10 * pwf1 + M11 * phf ) + M12;
    float Y3 = (M10 * pwf1 + M11 * phf1) + M12;

    float minX = fminf(fminf(X0, X1), fminf(X2, X3));
    float maxX = fmaxf(fmaxf(X0, X1), fmaxf(X2, X3));
    float minY = fminf(fminf(Y0, Y1), fminf(Y2, Y3));
    float maxY = fmaxf(fmaxf(Y0, Y1), fmaxf(Y2, Y3));

    // round = floor(x + 0.5)
    float left   = fmaxf(floorf(minX + 0.5f), 0.0f);
    float right  = fminf(floorf(maxX + 0.5f), (float)(W_ - 1));
    float top    = fmaxf(floorf(minY + 0.5f), 0.0f);
    float bottom = fminf(floorf(maxY + 0.5f), (float)(H_ - 1));

    float bcx = (left + right) * 0.5f;
    float bcy = (top + bottom) * 0.5f;
    float bl = floorf(bcx), br = ceilf(bcx);
    float bt = floorf(bcy), bb = ceilf(bcy);
    float rx = bcx - bl;
    float ry = bcy - bt;

    const float* fc = feat + (size_t)(b * C_ + c) * (H_ * W_);

    // branchless clamped gather with validity select
    auto gat = [&](float yi, float xi) -> float {
        bool valid = (yi > -1.0f) && (xi > -1.0f) && (yi < (float)H_) &&
                     (xi < (float)W_);
        int yc = (int)fminf(fmaxf(yi, 0.0f), (float)(H_ - 1));
        int xc = (int)fminf(fmaxf(xi, 0.0f), (float)(W_ - 1));
        float v = fc[yc * W_ + xc];
        return valid ? v : 0.0f;
    };

    float vlt = gat(bt, bl);
    float vrt = gat(bt, br);
    float vlb = gat(bb, bl);
    float vrb = gat(bb, br);

    float omrx = 1.0f - rx, omry = 1.0f - ry;
    float o = (((omrx * omry) * vlt + (rx * omry) * vrt) + (omrx * ry) * vlb) +
              (rx * ry) * vrb;

    out[idx] = o;
}

extern "C" void kernel_launch(void* const* d_in, const int* in_sizes, int n_in,
                              void* d_out, int out_size, void* d_ws,
                              size_t ws_size, hipStream_t stream) {
    const float* feat = (const float*)d_in[0];
    const float* rois = (const float*)d_in[1];
    float* out = (float*)d_out;
    float* g = (float*)d_ws;  // 1024 rois * 8 floats = 32 KB scratch
    int N = in_sizes[1] / 6;
    int total = out_size;  // N * C * PH * PW

    hipLaunchKernelGGL(roi_prep, dim3((N + 255) / 256), dim3(256), 0, stream,
                       rois, g, N);
    hipLaunchKernelGGL(rroi_main, dim3((total + 255) / 256), dim3(256), 0,
                       stream, feat, g, out, total);
}